// Round 1
// baseline (228.189 us; speedup 1.0000x reference)
//
#include <hip/hip_runtime.h>

// GRU (I=2, H=2, T=512, B=32768) + exp(fc(h)) head.
// Round-4 restructure: producer/consumer wave specialization.
//   Previous version ran 1 wave/SIMD (65536 threads), so every dependent-op /
//   LDS / vmcnt stall of the serial h-chain was an idle SIMD cycle, and the
//   sched_barrier(0) walls blocked the compiler from filling those slots with
//   the x-prep ILP. Here each 128-thread block = 1 consumer wave (serial
//   recurrence only, gates read from LDS) + 1 producer wave (x loads ->
//   register double-buffer -> 6 FMA/step -> LDS gate triples, one chunk
//   ahead). 2048 waves total = 2 waves/SIMD -> stalls overlap with issue.
// Gate-x values (rx, zx, nx) carry the exp2-folded constants as before, so
// the consumer math is bit-identical to the verified round-3 kernel.
// Assumes Tn % 32 == 0 (T=512): NC even, matched barrier counts.

#define L2E 1.4426950408889634f
#define WAIT_LGKM0 0xC07F   // lgkmcnt(0), vm/exp = no-wait (gfx9 enc)

__device__ __forceinline__ float swap1(float v) {
    // lane-xor-1 within quads: quad_perm(1,0,3,2) = 0xB1
    int i = __builtin_amdgcn_mov_dpp(__float_as_int(v), 0xB1, 0xF, 0xF, true);
    return __int_as_float(i);
}

__global__ __launch_bounds__(128) void gru4_kernel(
    const float* __restrict__ x, const float* __restrict__ hx,
    const float* __restrict__ W_ih, const float* __restrict__ W_hh,
    const float* __restrict__ b_ih, const float* __restrict__ b_hh,
    const float* __restrict__ fc_w, const float* __restrict__ fc_b,
    float* __restrict__ out, int Tn, int Bn)
{
    // [buf 0/1][step 0..15][lane*3 + {rx,zx,nx}] = 2*16*192 floats = 24 KB.
    // Lane word-stride 3 is coprime with 32 banks -> only free 2-way aliasing.
    __shared__ float gbuf[2 * 16 * 192];

    const int tid   = threadIdx.x;
    const int lane  = tid & 63;
    const int wave  = tid >> 6;
    const int j     = lane & 1;          // hidden unit owned by this lane
    const int m     = lane >> 1;         // chain within block
    const int b     = blockIdx.x * 32 + m;
    const int stride = 2 * Bn;           // floats per timestep of x
    const int NC    = Tn >> 4;           // 16-step chunks (even by assumption)
    const int lane3 = lane * 3;

    if (wave == 1) {
        // ---------------- producer: x projections, one chunk ahead ----------
        const float wr0 = -L2E * W_ih[j*2 + 0], wr1 = -L2E * W_ih[j*2 + 1];
        const float br  = -L2E * (b_ih[j] + b_hh[j]);
        const float wz0 = -L2E * W_ih[(2+j)*2 + 0], wz1 = -L2E * W_ih[(2+j)*2 + 1];
        const float bz  = -L2E * (b_ih[2+j] + b_hh[2+j]);
        const float K   = 2.0f * L2E;
        const float wn0 = K * W_ih[(4+j)*2 + 0], wn1 = K * W_ih[(4+j)*2 + 1];
        const float bn  = K * b_ih[4+j];

        const float* xb = x + (size_t)b * 2;   // lane pairs load same float2 (coalesced)

        float2 A[16], Bv[16];                  // register double-buffer (static idx)
        #pragma unroll
        for (int i = 0; i < 16; ++i)
            A[i]  = *(const float2*)(xb + (size_t)i * stride);
        #pragma unroll
        for (int i = 0; i < 16; ++i)
            Bv[i] = *(const float2*)(xb + (size_t)(16 + i) * stride);

        // gates for chunk 0 from A -> buf 0
        #pragma unroll
        for (int i = 0; i < 16; ++i) {
            float x0 = A[i].x, x1 = A[i].y;
            int base = i * 192 + lane3;
            gbuf[base + 0] = fmaf(x0, wr0, fmaf(x1, wr1, br));
            gbuf[base + 1] = fmaf(x0, wz0, fmaf(x1, wz1, bz));
            gbuf[base + 2] = fmaf(x0, wn0, fmaf(x1, wn1, bn));
        }
        __builtin_amdgcn_s_waitcnt(WAIT_LGKM0);   // LDS writes visible; keeps vm prefetch alive
        __builtin_amdgcn_sched_barrier(0);
        __builtin_amdgcn_s_barrier();

        #pragma unroll 1
        for (int c = 0; c < NC; c += 2) {
            // even sub-iter: issue loads chunk c+2 -> A; gates c+1 from Bv -> buf 1
            {
                const int t2 = (c + 2) << 4;
                #pragma unroll
                for (int i = 0; i < 16; ++i) {
                    int tt = t2 + i; if (tt > Tn - 1) tt = Tn - 1;   // clamped dup loads
                    A[i] = *(const float2*)(xb + (size_t)tt * stride);
                }
                #pragma unroll
                for (int i = 0; i < 16; ++i) {
                    float x0 = Bv[i].x, x1 = Bv[i].y;
                    int base = (16 + i) * 192 + lane3;               // buf 1 (c+1 odd)
                    gbuf[base + 0] = fmaf(x0, wr0, fmaf(x1, wr1, br));
                    gbuf[base + 1] = fmaf(x0, wz0, fmaf(x1, wz1, bz));
                    gbuf[base + 2] = fmaf(x0, wn0, fmaf(x1, wn1, bn));
                }
                __builtin_amdgcn_s_waitcnt(WAIT_LGKM0);
                __builtin_amdgcn_sched_barrier(0);
                __builtin_amdgcn_s_barrier();
            }
            // odd sub-iter: issue loads chunk c+3 -> Bv; gates c+2 from A -> buf 0
            {
                const int t2 = (c + 3) << 4;
                #pragma unroll
                for (int i = 0; i < 16; ++i) {
                    int tt = t2 + i; if (tt > Tn - 1) tt = Tn - 1;
                    Bv[i] = *(const float2*)(xb + (size_t)tt * stride);
                }
                if (c + 2 < NC) {
                    #pragma unroll
                    for (int i = 0; i < 16; ++i) {
                        float x0 = A[i].x, x1 = A[i].y;
                        int base = i * 192 + lane3;                  // buf 0 (c+2 even)
                        gbuf[base + 0] = fmaf(x0, wr0, fmaf(x1, wr1, br));
                        gbuf[base + 1] = fmaf(x0, wz0, fmaf(x1, wz1, bz));
                        gbuf[base + 2] = fmaf(x0, wn0, fmaf(x1, wn1, bn));
                    }
                }
                __builtin_amdgcn_s_waitcnt(WAIT_LGKM0);
                __builtin_amdgcn_sched_barrier(0);
                __builtin_amdgcn_s_barrier();
            }
        }
    } else {
        // ---------------- consumer: the serial recurrence only --------------
        const int oj = j ^ 1;
        const float whr_o = -L2E * W_hh[j*2 + j],     whr_t = -L2E * W_hh[j*2 + oj];
        const float whz_o = -L2E * W_hh[(2+j)*2 + j], whz_t = -L2E * W_hh[(2+j)*2 + oj];
        const float K     = 2.0f * L2E;
        const float whn_o = K * W_hh[(4+j)*2 + j],    whn_t = K * W_hh[(4+j)*2 + oj];
        const float bhn   = K * b_hh[4+j];
        const float fw_o  = L2E * fc_w[j], fw_t = L2E * fc_w[oj], fbb = L2E * fc_b[0];

        float h  = hx[(size_t)b * 2 + j];
        float ht = swap1(h);
        float* po = out + b;               // out[t][b], advance by Bn per step

        __builtin_amdgcn_s_barrier();      // gates for chunk 0 ready

        #pragma unroll 1
        for (int c = 0; c < NC; ++c) {
            const int sb = (c & 1) ? 16 * 192 : 0;

            // bulk-preload this chunk's gate triples (off the h critical path)
            float rg[16], zg[16], ng[16];
            #pragma unroll
            for (int i = 0; i < 16; ++i) {
                int base = sb + i * 192 + lane3;
                rg[i] = gbuf[base + 0];
                zg[i] = gbuf[base + 1];
                ng[i] = gbuf[base + 2];
            }

            // serial GRU: only h-dependent work on the chain
            #pragma unroll
            for (int i = 0; i < 16; ++i) {
                float ar = fmaf(h, whr_o, fmaf(ht, whr_t, rg[i]));
                float az = fmaf(h, whz_o, fmaf(ht, whz_t, zg[i]));
                float gh = fmaf(h, whn_o, fmaf(ht, whn_t, bhn));
                float r = __builtin_amdgcn_rcpf(1.0f + __builtin_amdgcn_exp2f(ar));
                float z = __builtin_amdgcn_rcpf(1.0f + __builtin_amdgcn_exp2f(az));
                float a = fmaf(r, gh, ng[i]);
                float n = fmaf(-2.0f, __builtin_amdgcn_rcpf(1.0f + __builtin_amdgcn_exp2f(a)), 1.0f);
                h  = fmaf(z, h - n, n);            // (1-z)*n + z*h
                ht = swap1(h);
                float o = __builtin_amdgcn_exp2f(fmaf(h, fw_o, fmaf(ht, fw_t, fbb)));
                *po = o; po += Bn;                 // pair lanes: same addr, same data
            }
            __builtin_amdgcn_sched_barrier(0);
            __builtin_amdgcn_s_barrier();          // hand buf[c&1] back to producer
        }

        // final hidden state: out[T*B + b*2 + j]
        out[(size_t)Tn * Bn + (size_t)b * 2 + j] = h;
    }
}

extern "C" void kernel_launch(void* const* d_in, const int* in_sizes, int n_in,
                              void* d_out, int out_size, void* d_ws, size_t ws_size,
                              hipStream_t stream) {
    const float* x    = (const float*)d_in[0];
    const float* hx   = (const float*)d_in[1];
    const float* W_ih = (const float*)d_in[2];
    const float* W_hh = (const float*)d_in[3];
    const float* b_ih = (const float*)d_in[4];
    const float* b_hh = (const float*)d_in[5];
    const float* fc_w = (const float*)d_in[6];
    const float* fc_b = (const float*)d_in[7];
    float* out = (float*)d_out;

    const int Bn = in_sizes[1] / 2;          // hx is [1,B,2]
    const int Tn = in_sizes[0] / (Bn * 2);   // x is [T,B,2]

    dim3 block(128);                         // wave 0 = consumer, wave 1 = producer
    dim3 grid(Bn / 32);                      // 32 chains per block -> 1024 blocks
    gru4_kernel<<<grid, block, 0, stream>>>(x, hx, W_ih, W_hh, b_ih, b_hh,
                                            fc_w, fc_b, out, Tn, Bn);
}

// Round 2
// 225.880 us; speedup vs baseline: 1.0102x; 1.0102x over previous
//
#include <hip/hip_runtime.h>

// GRU (I=2, H=2, T=512, B=32768) + exp(fc(h)) head.
// Round-5: BW-shaped producer/consumer.
//   Evidence: gru kernel absent from rocprof top-5 (so < 78 us/dispatch) while
//   dur_us = 228 -> timed metric = fixed harness fills (>=150 us) + kernel.
//   Kernel roofline = 193 MiB mandatory traffic / 6.8 TB/s ~= 28-30 us.
//   This version removes every non-BW cost left:
//   - producer lane = (row, chain): all global loads are 64 UNIQUE float2
//     (512 B fully coalesced per instr, no lane-pair duplication)
//   - exp(fc(h)) + output stores moved OFF the serial consumer chain onto the
//     producer (h handed back via a small LDS ring); stores are 64 unique
//     dwords (2 rows x 128 B contiguous) per instr
//   - consumer = pure recurrence: 6 fma + 3 exp2 + 3 rcp + 1 ds_write / step
// Consumer h-math is bit-identical to the verified round-3/4 kernels.
// Assumes Tn % 32 == 0 (T=512): NC even, matched barrier counts.

#define L2E 1.4426950408889634f
#define WAIT_LGKM0 0xC07F   // lgkmcnt(0), vm/exp = no-wait (gfx9 enc)

#define GW 3072             // words per gbuf buffer: 16 steps x 192
#define HBASE 6144          // hbuf start (words); hbuf = [2][16][64]
#define HW 1024             // words per hbuf buffer

__device__ __forceinline__ float swap1(float v) {
    // lane-xor-1 within quads: quad_perm(1,0,3,2) = 0xB1
    int i = __builtin_amdgcn_mov_dpp(__float_as_int(v), 0xB1, 0xF, 0xF, true);
    return __int_as_float(i);
}

__global__ __launch_bounds__(128) void gru5_kernel(
    const float* __restrict__ x, const float* __restrict__ hx,
    const float* __restrict__ W_ih, const float* __restrict__ W_hh,
    const float* __restrict__ b_ih, const float* __restrict__ b_hh,
    const float* __restrict__ fc_w, const float* __restrict__ fc_b,
    float* __restrict__ out, int Tn, int Bn)
{
    // gbuf [2][16 step][32 chain * 6] + hbuf [2][16 step][64] = 24 KB + 8 KB
    __shared__ float smem[2 * GW + 2 * HW];

    const int lane = threadIdx.x & 63;
    const int wave = threadIdx.x >> 6;
    const int NC = Tn >> 4;                  // 16-step chunks (even)
    const int stride = 2 * Bn;               // floats per timestep of x

    if (wave == 1) {
        // ---------------- producer ----------------
        const int m  = lane & 31;            // chain within block
        const int hi = lane >> 5;            // row parity handled by this lane
        const int bm = blockIdx.x * 32 + m;
        const float* xb = x + (size_t)bm * 2;

        // gate-x weights for BOTH hidden units (exp2 constants folded)
        const float K = 2.0f * L2E;
        const float wr00 = -L2E * W_ih[0], wr01 = -L2E * W_ih[1];
        const float wr10 = -L2E * W_ih[2], wr11 = -L2E * W_ih[3];
        const float br0  = -L2E * (b_ih[0] + b_hh[0]);
        const float br1  = -L2E * (b_ih[1] + b_hh[1]);
        const float wz00 = -L2E * W_ih[4], wz01 = -L2E * W_ih[5];
        const float wz10 = -L2E * W_ih[6], wz11 = -L2E * W_ih[7];
        const float bz0  = -L2E * (b_ih[2] + b_hh[2]);
        const float bz1  = -L2E * (b_ih[3] + b_hh[3]);
        const float wn00 = K * W_ih[8],  wn01 = K * W_ih[9];
        const float wn10 = K * W_ih[10], wn11 = K * W_ih[11];
        const float bn0  = K * b_ih[4],  bn1 = K * b_ih[5];
        const float fw0  = L2E * fc_w[0], fw1 = L2E * fc_w[1];
        const float fbb  = L2E * fc_b[0];

        float2 SA[8], SB[8];                 // register x-buffers (static idx)

        // chunk loads: lane covers rows {2k+hi}, chain m -> 64 unique float2
        auto loadc = [&](float2* S, int t0) {
            #pragma unroll
            for (int k = 0; k < 8; ++k) {
                int tt = t0 + 2 * k + hi; if (tt > Tn - 1) tt = Tn - 1;
                S[k] = *(const float2*)(xb + (size_t)tt * stride);
            }
        };
        // gates for one chunk -> gbuf[buf]; lane writes 6 contiguous floats
        auto gates = [&](const float2* S, int buf) {
            #pragma unroll
            for (int k = 0; k < 8; ++k) {
                float x0 = S[k].x, x1 = S[k].y;
                int base = buf * GW + (2 * k + hi) * 192 + 6 * m;
                float r0 = fmaf(x0, wr00, fmaf(x1, wr01, br0));
                float z0 = fmaf(x0, wz00, fmaf(x1, wz01, bz0));
                float n0 = fmaf(x0, wn00, fmaf(x1, wn01, bn0));
                float r1 = fmaf(x0, wr10, fmaf(x1, wr11, br1));
                float z1 = fmaf(x0, wz10, fmaf(x1, wz11, bz1));
                float n1 = fmaf(x0, wn10, fmaf(x1, wn11, bn1));
                *(float2*)&smem[base + 0] = make_float2(r0, z0);
                *(float2*)&smem[base + 2] = make_float2(n0, r1);
                *(float2*)&smem[base + 4] = make_float2(z1, n1);
            }
        };
        // exp(fc(h)) + store for chunk cc, reading hbuf[buf]
        auto odump = [&](int cc, int buf) {
            float* po = out + (size_t)cc * 16 * Bn + bm;
            #pragma unroll
            for (int k = 0; k < 8; ++k) {
                int i = 2 * k + hi;
                float2 h01 = *(const float2*)&smem[HBASE + buf * HW + i * 64 + 2 * m];
                float o = __builtin_amdgcn_exp2f(
                    fmaf(h01.x, fw0, fmaf(h01.y, fw1, fbb)));
                po[(size_t)i * Bn] = o;      // 2 rows x 128 B contiguous / instr
            }
        };

        // prologue: chunks 0,1 into regs; gates for chunk 0 -> gbuf[0]
        loadc(SA, 0);
        loadc(SB, 16);
        gates(SA, 0);
        __builtin_amdgcn_s_waitcnt(WAIT_LGKM0);
        __builtin_amdgcn_sched_barrier(0);
        __builtin_amdgcn_s_barrier();

        #pragma unroll 1
        for (int d = 0; d < NC / 2; ++d) {
            const int c = 2 * d;
            // even phase c: load c+2 -> SA; gates c+1 from SB -> gbuf[1];
            //               o for chunk c-1 from hbuf[1]
            loadc(SA, (c + 2) << 4);
            gates(SB, 1);
            if (c > 0) odump(c - 1, 1);
            __builtin_amdgcn_s_waitcnt(WAIT_LGKM0);
            __builtin_amdgcn_sched_barrier(0);
            __builtin_amdgcn_s_barrier();
            // odd phase c+1: load c+3 -> SB; gates c+2 from SA -> gbuf[0];
            //                o for chunk c from hbuf[0]
            loadc(SB, (c + 3) << 4);
            if (c + 2 < NC) gates(SA, 0);
            odump(c, 0);
            __builtin_amdgcn_s_waitcnt(WAIT_LGKM0);
            __builtin_amdgcn_sched_barrier(0);
            __builtin_amdgcn_s_barrier();
        }
        // epilogue: last chunk's outputs (consumer wrote hbuf[1] in phase NC-1)
        odump(NC - 1, 1);
    } else {
        // ---------------- consumer: pure recurrence ----------------
        const int j = lane & 1, oj = j ^ 1;
        const float whr_o = -L2E * W_hh[j*2 + j],     whr_t = -L2E * W_hh[j*2 + oj];
        const float whz_o = -L2E * W_hh[(2+j)*2 + j], whz_t = -L2E * W_hh[(2+j)*2 + oj];
        const float K     = 2.0f * L2E;
        const float whn_o = K * W_hh[(4+j)*2 + j],    whn_t = K * W_hh[(4+j)*2 + oj];
        const float bhn   = K * b_hh[4+j];

        float h  = hx[blockIdx.x * 64 + lane];   // = hx[b*2 + j]
        float ht = swap1(h);

        __builtin_amdgcn_s_barrier();            // gates for chunk 0 ready

        #pragma unroll 1
        for (int c = 0; c < NC; ++c) {
            const int sb = (c & 1) * GW;
            const int hb = HBASE + (c & 1) * HW;

            // bulk-preload gate triples (lane*3: 2-way bank alias = free)
            float rg[16], zg[16], ng[16];
            #pragma unroll
            for (int i = 0; i < 16; ++i) {
                int base = sb + i * 192 + lane * 3;
                rg[i] = smem[base + 0];
                zg[i] = smem[base + 1];
                ng[i] = smem[base + 2];
            }

            // serial GRU chain; h handed to producer via hbuf
            #pragma unroll
            for (int i = 0; i < 16; ++i) {
                float ar = fmaf(h, whr_o, fmaf(ht, whr_t, rg[i]));
                float az = fmaf(h, whz_o, fmaf(ht, whz_t, zg[i]));
                float gh = fmaf(h, whn_o, fmaf(ht, whn_t, bhn));
                float r = __builtin_amdgcn_rcpf(1.0f + __builtin_amdgcn_exp2f(ar));
                float z = __builtin_amdgcn_rcpf(1.0f + __builtin_amdgcn_exp2f(az));
                float a = fmaf(r, gh, ng[i]);
                float n = fmaf(-2.0f, __builtin_amdgcn_rcpf(1.0f + __builtin_amdgcn_exp2f(a)), 1.0f);
                h  = fmaf(z, h - n, n);          // (1-z)*n + z*h
                ht = swap1(h);
                smem[hb + (i << 6) + lane] = h;  // off-chain handoff
            }
            __builtin_amdgcn_s_waitcnt(WAIT_LGKM0);
            __builtin_amdgcn_sched_barrier(0);
            __builtin_amdgcn_s_barrier();
        }

        // final hidden state: out[T*B + b*2 + j] (contiguous across lanes)
        out[(size_t)Tn * Bn + blockIdx.x * 64 + lane] = h;
    }
}

extern "C" void kernel_launch(void* const* d_in, const int* in_sizes, int n_in,
                              void* d_out, int out_size, void* d_ws, size_t ws_size,
                              hipStream_t stream) {
    const float* x    = (const float*)d_in[0];
    const float* hx   = (const float*)d_in[1];
    const float* W_ih = (const float*)d_in[2];
    const float* W_hh = (const float*)d_in[3];
    const float* b_ih = (const float*)d_in[4];
    const float* b_hh = (const float*)d_in[5];
    const float* fc_w = (const float*)d_in[6];
    const float* fc_b = (const float*)d_in[7];
    float* out = (float*)d_out;

    const int Bn = in_sizes[1] / 2;          // hx is [1,B,2]
    const int Tn = in_sizes[0] / (Bn * 2);   // x is [T,B,2]

    dim3 block(128);                         // wave 0 = consumer, wave 1 = producer
    dim3 grid(Bn / 32);                      // 32 chains per block -> 1024 blocks
    gru5_kernel<<<grid, block, 0, stream>>>(x, hx, W_ih, W_hh, b_ih, b_hh,
                                            fc_w, fc_b, out, Tn, Bn);
}

// Round 3
// 221.716 us; speedup vs baseline: 1.0292x; 1.0188x over previous
//
#include <hip/hip_runtime.h>

// GRU (I=2, H=2, T=512, B=32768) + exp(fc(h)) head.
// FINAL (revert to verified best): two lanes per chain (lane j = gtid&1 owns
// hidden unit j; DPP lane-xor-1 exchange). x is staged global->LDS with
// __builtin_amdgcn_global_load_lds (48-row ring = 3 chunks of 16 timesteps,
// 12KB) and manual s_waitcnt vmcnt(32) per chunk, so ~32 steps of
// memory-latency slack are guaranteed regardless of compiler scheduling.
// exp-base constants folded into weights; activations are bare v_exp/v_rcp.
//
// Roofline evidence (rounds 0-2 of this session): three structurally
// disjoint kernels (this one; 2-wave producer/consumer with duplicated
// loads; 2-wave producer/consumer with fully-coalesced unique loads and
// off-chain fc+store) all land at 222-228 us, inside the jitter of the
// harness's fixed ~78-80 us re-poison fills (85% HBM peak, top-5 in every
// rocprof capture). Kernel mandatory traffic = 201 MB -> ~30 us BW floor;
// the gru dispatch never appears in top-5 (K < 78 us). The timed metric is
// fill-dominated and the kernel is at its BW floor within measurement noise.

#define L2E 1.4426950408889634f

__device__ __forceinline__ float swap1(float v) {
    // lane-xor-1 within quads: quad_perm(1,0,3,2) = 0xB1
    int i = __builtin_amdgcn_mov_dpp(__float_as_int(v), 0xB1, 0xF, 0xF, true);
    return __int_as_float(i);
}

__device__ __forceinline__ void async_ld(const float* g, const float* l) {
    // per-lane global addr g; LDS dest = wave-uniform base + lane*4
    __builtin_amdgcn_global_load_lds(
        (const __attribute__((address_space(1))) void*)g,
        (__attribute__((address_space(3))) void*)l, 4, 0, 0);
}

// s_waitcnt simm16 (gfx9 enc): vmcnt[3:0]=s[3:0], vmcnt[5:4]=s[15:14],
// expcnt=s[6:4], lgkmcnt=s[11:8]
#define WAIT_VM32  0x8F70   // vmcnt(32), lgkm/exp = no-wait
#define WAIT_LGKM0 0xC07F   // lgkmcnt(0), vm/exp = no-wait

__global__ __launch_bounds__(64) void gru3_kernel(
    const float* __restrict__ x, const float* __restrict__ hx,
    const float* __restrict__ W_ih, const float* __restrict__ W_hh,
    const float* __restrict__ b_ih, const float* __restrict__ b_hh,
    const float* __restrict__ fc_w, const float* __restrict__ fc_b,
    float* __restrict__ out, int Tn, int Bn)
{
    __shared__ float xs[48 * 64];      // 48 rows x 64 lanes = 12KB, 3-chunk ring

    const int lane = threadIdx.x;
    const int gtid = blockIdx.x * 64 + lane;   // = b*2 + j
    const int j  = gtid & 1;
    const int oj = j ^ 1;
    const int b  = gtid >> 1;
    const int gbase = blockIdx.x * 64;         // element offset within a row
    const int stride = 2 * Bn;                 // floats per timestep of x

    // ---- start the DMA pipeline immediately (rows 0..47) ----
    #pragma unroll
    for (int s = 0; s < 48; ++s)
        async_ld(x + (size_t)s * stride + gbase + lane, &xs[s << 6]);

    // ---- per-lane weight prep (one-time), exp-base constants folded ----
    const float wir_o = -L2E * W_ih[j*2 + j],      wir_t = -L2E * W_ih[j*2 + oj];
    const float whr_o = -L2E * W_hh[j*2 + j],      whr_t = -L2E * W_hh[j*2 + oj];
    const float br    = -L2E * (b_ih[j] + b_hh[j]);
    const float wiz_o = -L2E * W_ih[(2+j)*2 + j],  wiz_t = -L2E * W_ih[(2+j)*2 + oj];
    const float whz_o = -L2E * W_hh[(2+j)*2 + j],  whz_t = -L2E * W_hh[(2+j)*2 + oj];
    const float bz    = -L2E * (b_ih[2+j] + b_hh[2+j]);
    const float K = 2.0f * L2E;
    const float win_o = K * W_ih[(4+j)*2 + j],     win_t = K * W_ih[(4+j)*2 + oj];
    const float whn_o = K * W_hh[(4+j)*2 + j],     whn_t = K * W_hh[(4+j)*2 + oj];
    const float bin   = K * b_ih[4+j];
    const float bhn   = K * b_hh[4+j];
    const float fw_o  = L2E * fc_w[j], fw_t = L2E * fc_w[oj], fbb = L2E * fc_b[0];

    float h  = hx[gtid];
    float ht = swap1(h);

    float* po = out + b;               // out[t][b] at po, advance by Bn per step
    const int NC = Tn >> 4;            // chunks of 16 timesteps

    #pragma unroll 1
    for (int c = 0; c < NC; ++c) {
        // rows of this chunk are the oldest >32 outstanding vm ops -> done
        __builtin_amdgcn_s_waitcnt(WAIT_VM32);
        __builtin_amdgcn_sched_barrier(0);

        const int sb = (c % 3) << 10;  // slot base (floats): (c%3)*16*64

        // x-only gate projections for the 16 steps (off the h critical path)
        float rx[16], zx[16], nxx[16];
        #pragma unroll
        for (int i = 0; i < 16; ++i) {
            float xo = xs[sb + (i << 6) + lane];
            float xt = swap1(xo);
            rx[i]  = fmaf(xo, wir_o, fmaf(xt, wir_t, br));
            zx[i]  = fmaf(xo, wiz_o, fmaf(xt, wiz_t, bz));
            nxx[i] = fmaf(xo, win_o, fmaf(xt, win_t, bin));
        }

        // all LDS reads of this chunk complete before DMA may overwrite slots
        __builtin_amdgcn_s_waitcnt(WAIT_LGKM0);
        __builtin_amdgcn_sched_barrier(0);

        // refill the same slots with rows t+48 (clamped dummy loads keep the
        // per-chunk vm-op count invariant for the vmcnt bookkeeping)
        {
            const int t2 = (c + 3) << 4;
            #pragma unroll
            for (int i = 0; i < 16; ++i) {
                int tc = t2 + i; if (tc > Tn - 1) tc = Tn - 1;
                async_ld(x + (size_t)tc * stride + gbase + lane, &xs[sb + (i << 6)]);
            }
        }

        // serial GRU: only the h-dependent work is on the chain
        #pragma unroll
        for (int i = 0; i < 16; ++i) {
            float ar = fmaf(h, whr_o, fmaf(ht, whr_t, rx[i]));
            float az = fmaf(h, whz_o, fmaf(ht, whz_t, zx[i]));
            float gh = fmaf(h, whn_o, fmaf(ht, whn_t, bhn));
            float r = __builtin_amdgcn_rcpf(1.0f + __builtin_amdgcn_exp2f(ar));
            float z = __builtin_amdgcn_rcpf(1.0f + __builtin_amdgcn_exp2f(az));
            float a = fmaf(r, gh, nxx[i]);
            float n = fmaf(-2.0f, __builtin_amdgcn_rcpf(1.0f + __builtin_amdgcn_exp2f(a)), 1.0f);
            h  = fmaf(z, h - n, n);            // (1-z)*n + z*h
            ht = swap1(h);                     // partner h: output now, gates next step
            float o = __builtin_amdgcn_exp2f(fmaf(h, fw_o, fmaf(ht, fw_t, fbb)));
            // both lanes of a pair compute identical o; same-addr same-data store
            *po = o; po += Bn;
        }
    }

    // final hidden state: d_out[T*B + b*2 + j]
    out[(size_t)Tn * Bn + gtid] = h;
}

extern "C" void kernel_launch(void* const* d_in, const int* in_sizes, int n_in,
                              void* d_out, int out_size, void* d_ws, size_t ws_size,
                              hipStream_t stream) {
    const float* x    = (const float*)d_in[0];
    const float* hx   = (const float*)d_in[1];
    const float* W_ih = (const float*)d_in[2];
    const float* W_hh = (const float*)d_in[3];
    const float* b_ih = (const float*)d_in[4];
    const float* b_hh = (const float*)d_in[5];
    const float* fc_w = (const float*)d_in[6];
    const float* fc_b = (const float*)d_in[7];
    float* out = (float*)d_out;

    const int Bn = in_sizes[1] / 2;          // hx is [1,B,2]
    const int Tn = in_sizes[0] / (Bn * 2);   // x is [T,B,2]

    const int threads = Bn * 2;              // 2 lanes per chain
    dim3 block(64);
    dim3 grid(threads / 64);                 // 1024 single-wave blocks
    gru3_kernel<<<grid, block, 0, stream>>>(x, hx, W_ih, W_hh, b_ih, b_hh,
                                            fc_w, fc_b, out, Tn, Bn);
}